// Round 3
// baseline (870.673 us; speedup 1.0000x reference)
//
#include <hip/hip_runtime.h>
#include <math.h>

typedef unsigned short u16;
typedef __bf16 bf16x8 __attribute__((ext_vector_type(8)));
typedef float f32x4 __attribute__((ext_vector_type(4)));

#define T_TOK 4096
#define DIMD 2048
#define HIDD 1024
#define NEXP 16
#define RMAX 10240
#define MAXBLK 160

__device__ __forceinline__ u16 f2b(float f) {
  unsigned u = __builtin_bit_cast(unsigned, f);
  unsigned r = (u + 0x7FFFu + ((u >> 16) & 1u)) >> 16;  // RNE
  return (u16)r;
}
__device__ __forceinline__ float b2f(u16 u) {
  return __builtin_bit_cast(float, (unsigned)u << 16);
}
__device__ __forceinline__ void gld16(const void* g, void* l) {
  __builtin_amdgcn_global_load_lds(
      (const __attribute__((address_space(1))) void*)g,
      (__attribute__((address_space(3))) void*)l, 16, 0, 0);
}

// ---------------- small kernels ----------------

__global__ void k_init(int* perm, int* cnt, int* fill) {
  int i = blockIdx.x * blockDim.x + threadIdx.x;
  if (i < RMAX) perm[i] = -1;
  if (i < NEXP) { cnt[i] = 0; fill[i] = 0; }
}

__global__ void k_cvt(const float* __restrict__ x, u16* __restrict__ xb) {
  const int i = blockIdx.x * blockDim.x + threadIdx.x;
  const float4 v = ((const float4*)x)[i];
  union { u16 u[4]; unsigned long long q; } t;
  t.u[0] = f2b(v.x); t.u[1] = f2b(v.y); t.u[2] = f2b(v.z); t.u[3] = f2b(v.w);
  ((unsigned long long*)xb)[i] = t.q;
}

// transpose+convert: W fp32 [E][K][N] -> Wt bf16 [e][n][k]
__global__ __launch_bounds__(256)
void k_tr(const float* __restrict__ W, u16* __restrict__ Wt,
          int K, int N, long estride, int ld_out) {
  __shared__ float t[64][65];
  const int e = blockIdx.z;
  const float* Win = W + (size_t)e * (size_t)K * (size_t)N;
  u16* Wo = Wt + (size_t)e * (size_t)estride;
  const int n0 = blockIdx.x * 64, k0 = blockIdx.y * 64;
  const int r = threadIdx.x >> 4;
  const int c = (threadIdx.x & 15) * 4;
#pragma unroll
  for (int p = 0; p < 4; ++p) {
    const int kk = p * 16 + r;
    const float4 v = *(const float4*)&Win[(size_t)(k0 + kk) * N + n0 + c];
    t[kk][c] = v.x; t[kk][c + 1] = v.y; t[kk][c + 2] = v.z; t[kk][c + 3] = v.w;
  }
  __syncthreads();
#pragma unroll
  for (int p = 0; p < 4; ++p) {
    const int nn = p * 16 + r;
    ushort4 o;
    o.x = f2b(t[c + 0][nn]); o.y = f2b(t[c + 1][nn]);
    o.z = f2b(t[c + 2][nn]); o.w = f2b(t[c + 3][nn]);
    *(ushort4*)&Wo[(size_t)(n0 + nn) * ld_out + k0 + c] = o;
  }
}

__global__ __launch_bounds__(256)
void k_gate(const float* __restrict__ x, const float* __restrict__ gw,
            int* __restrict__ top2i, float* __restrict__ top2w,
            int* __restrict__ cnt, float* __restrict__ partial) {
  const int e = threadIdx.x & 15;
  const int tt = threadIdx.x >> 4;
  const int t = blockIdx.x * 16 + tt;
  const float* xp = x + (size_t)t * DIMD;
  float acc = 0.f;
#pragma unroll 8
  for (int k = 0; k < DIMD; ++k) acc = fmaf(xp[k], gw[k * NEXP + e], acc);
  __shared__ float lg[16][17];
  __shared__ float pr[16][17];
  lg[tt][e] = acc;
  __syncthreads();
  if (e == 0) {
    float l[16];
    float mx = -1e30f;
    for (int j = 0; j < 16; ++j) { l[j] = lg[tt][j]; mx = fmaxf(mx, l[j]); }
    float s = 0.f;
    for (int j = 0; j < 16; ++j) { l[j] = expf(l[j] - mx); s += l[j]; }
    const float inv = 1.f / s;
    float p1 = -1.f, p2 = -1.f; int i1 = 0, i2 = 0;
    for (int j = 0; j < 16; ++j) {
      const float p = l[j] * inv;
      pr[tt][j] = p;
      if (p > p1) { p2 = p1; i2 = i1; p1 = p; i1 = j; }
      else if (p > p2) { p2 = p; i2 = j; }
    }
    const float wsum = p1 + p2;
    top2i[t * 2 + 0] = i1;
    top2i[t * 2 + 1] = i2;
    top2w[t * 2 + 0] = p1 / wsum;
    top2w[t * 2 + 1] = p2 / wsum;
    atomicAdd(&cnt[i1], 1);
    atomicAdd(&cnt[i2], 1);
  }
  __syncthreads();
  if (tt == 0) {
    float s = 0.f;
    for (int j = 0; j < 16; ++j) s += pr[j][e];
    partial[blockIdx.x * 16 + e] = s;
  }
}

__global__ __launch_bounds__(256)
void k_aux(const float* __restrict__ partial, float* __restrict__ auxOut) {
  __shared__ float s[16][17];
  const int e = threadIdx.x & 15, c = threadIdx.x >> 4;
  float a = 0.f;
  for (int b = c; b < 256; b += 16) a += partial[b * 16 + e];
  s[c][e] = a;
  __syncthreads();
  if (threadIdx.x == 0) {
    float aux = 0.f;
    for (int j = 0; j < 16; ++j) {
      float tot = 0.f;
      for (int cc = 0; cc < 16; ++cc) tot += s[cc][j];
      const float m = tot / (float)T_TOK;
      aux += m * m;
    }
    auxOut[0] = aux * (float)NEXP;
  }
}

// Build padded offsets + block tables for the merged up/down dispatches.
// tU: [0..63] shared-up (e=16+s, r0=token block), [64..] routed (e, hbR row block)
// tD: [0..31] shared-down (e=16, r0=token block), [32..] routed
__global__ void k_off(const int* __restrict__ cnt, int* __restrict__ offs,
                      int* __restrict__ tUe, int* __restrict__ tUr,
                      int* __restrict__ tDe, int* __restrict__ tDr,
                      int* __restrict__ nblk) {
  if (threadIdx.x != 0 || blockIdx.x != 0) return;
  for (int s = 0; s < 2; ++s)
    for (int i = 0; i < 32; ++i) { tUe[s * 32 + i] = 16 + s; tUr[s * 32 + i] = i * 128; }
  for (int i = 0; i < 32; ++i) { tDe[i] = 16; tDr[i] = i * 128; }
  int o = 0, nb = 0;
  for (int e = 0; e < NEXP; ++e) {
    offs[e] = o;
    const int b = (cnt[e] + 127) / 128;
    for (int i = 0; i < b; ++i) {
      tUe[64 + nb] = e; tUr[64 + nb] = o + i * 128;
      tDe[32 + nb] = e; tDr[32 + nb] = o + i * 128;
      ++nb;
    }
    o += b * 128;
  }
  offs[NEXP] = o;
  nblk[0] = 64 + nb;
  nblk[1] = 32 + nb;
}

__global__ void k_fill(const int* __restrict__ top2i, const float* __restrict__ top2w,
                       const int* __restrict__ offs, int* __restrict__ fill,
                       int* __restrict__ perm, float* __restrict__ wrow,
                       int* __restrict__ slot) {
  const int id = blockIdx.x * blockDim.x + threadIdx.x;
  if (id >= T_TOK * 2) return;
  const int e = top2i[id];
  const int pos = atomicAdd(&fill[e], 1);
  const int r = offs[e] + pos;
  perm[r] = id >> 1;
  wrow[r] = top2w[id];
  slot[r] = id & 1;
}

// ---------------- GEMM ----------------
// 128x128 tile, BK=64, global_load_lds 16B staging, XOR-swizzled LDS chunks.
// PHASE 0 (up):   e<16: A=xb gathered via perm, B=w1t[e], silu->bf16 to hbR
//                 e>=16: A=xb rows=tokens, B=sw1t[e-16], silu->bf16 to hbS col (e-16)*1024
// PHASE 1 (down): e=16: A=hbS, B=sw2ct, fp32 store to out
//                 e<16: A=hbR, B=w2t[e], weighted bf16 store to y[(t*2+slot)]
template<int PHASE>
__global__ __launch_bounds__(256)
void k_gemm(const u16* __restrict__ Ar, const u16* __restrict__ Ash,
            const u16* __restrict__ Wr, const u16* __restrict__ Wsh,
            void* __restrict__ oR, void* __restrict__ oS,
            const int* __restrict__ perm, const float* __restrict__ wrow,
            const int* __restrict__ slot,
            const int* __restrict__ te, const int* __restrict__ tr,
            const int* __restrict__ nblk) {
  __shared__ u16 LA[128 * 64];
  __shared__ u16 LB[128 * 64];
  __shared__ int rowS[128];

  const int bx = blockIdx.x, by = blockIdx.y;
  if (bx >= nblk[PHASE]) return;
  const int e = te[bx];
  const int r0 = tr[bx];
  const bool sh = (e >= 16);

  const u16* A; const u16* B; int lda, K, ldb;
  if (PHASE == 0) {
    A = Ar; lda = 2048; K = 2048; ldb = 2048;
    B = sh ? (Wsh + (size_t)(e - 16) * (1024 * 2048))
           : (Wr + (size_t)e * (1024 * 2048));
  } else {
    if (sh) { A = Ash; lda = 2048; K = 2048; ldb = 2048; B = Wsh; }
    else    { A = Ar;  lda = 1024; K = 1024; ldb = 1024; B = Wr + (size_t)e * (2048 * 1024); }
  }

  const int tid = threadIdx.x;
  if (tid < 128) {
    int v;
    if (PHASE == 0 && !sh) { const int p = perm[r0 + tid]; v = (p < 0) ? 0 : p; }
    else v = r0 + tid;
    rowS[tid] = v;
  }
  __syncthreads();

  const int w = tid >> 6, lane = tid & 63;
  const int sr = lane >> 3;          // subrow 0..7
  const int sc = lane & 7;           // chunk 0..7
  const int kx = (sc ^ sr) << 3;     // swizzled k element offset for staging
  const u16* ap[4];
#pragma unroll
  for (int i = 0; i < 4; ++i)
    ap[i] = A + (size_t)rowS[w * 32 + i * 8 + sr] * lda + kx;
  const int n0 = by * 128;
  const u16* bp = B + (size_t)(n0 + w * 32 + sr) * ldb + kx;
  u16* la = &LA[w * 32 * 64];
  u16* lb = &LB[w * 32 * 64];

  f32x4 acc[4][4];
#pragma unroll
  for (int i = 0; i < 4; ++i)
#pragma unroll
    for (int j = 0; j < 4; ++j) {
      acc[i][j][0] = 0.f; acc[i][j][1] = 0.f; acc[i][j][2] = 0.f; acc[i][j][3] = 0.f;
    }

  const int wr = (w >> 1) * 64, wc = (w & 1) * 64;
  const int lm = lane & 15, lq = lane >> 4;
  const int c0 = lq ^ (lm & 7);      // swizzled chunk for k-half 0 (h=1 is c0^4)
  const int aO = (wr + lm) * 64;
  const int bO = (wc + lm) * 64;

  for (int k0 = 0; k0 < K; k0 += 64) {
#pragma unroll
    for (int i = 0; i < 4; ++i) {
      gld16(ap[i] + k0, la + i * 512);
      gld16(bp + (size_t)i * 8 * ldb + k0, lb + i * 512);
    }
    __syncthreads();
#pragma unroll
    for (int h = 0; h < 2; ++h) {
      const int cc = (h ? (c0 ^ 4) : c0) << 3;
      bf16x8 af[4], bq[4];
#pragma unroll
      for (int i = 0; i < 4; ++i) af[i] = *(const bf16x8*)&LA[aO + cc + i * 1024];
#pragma unroll
      for (int j = 0; j < 4; ++j) bq[j] = *(const bf16x8*)&LB[bO + cc + j * 1024];
#pragma unroll
      for (int i = 0; i < 4; ++i)
#pragma unroll
        for (int j = 0; j < 4; ++j)
          acc[i][j] = __builtin_amdgcn_mfma_f32_16x16x32_bf16(af[i], bq[j], acc[i][j], 0, 0, 0);
    }
    __syncthreads();
  }

#pragma unroll
  for (int i = 0; i < 4; ++i) {
    const int lr0 = wr + i * 16 + lq * 4;   // C/D: row=(lane>>4)*4+r, col=lane&15
#pragma unroll
    for (int j = 0; j < 4; ++j) {
      const int gc = n0 + wc + j * 16 + lm;
#pragma unroll
      for (int r = 0; r < 4; ++r) {
        const float v = acc[i][j][r];
        const int lrow = lr0 + r;
        if (PHASE == 0) {
          const float sv = v / (1.f + expf(-v));
          if (!sh) ((u16*)oR)[(size_t)(r0 + lrow) * HIDD + gc] = f2b(sv);
          else ((u16*)oS)[(size_t)(r0 + lrow) * DIMD + (e - 16) * HIDD + gc] = f2b(sv);
        } else {
          if (sh) {
            ((float*)oS)[(size_t)(r0 + lrow) * DIMD + gc] = v;
          } else {
            const int rr = r0 + lrow;
            const int t = perm[rr];
            if (t >= 0)
              ((u16*)oR)[((size_t)t * 2 + slot[rr]) * DIMD + gc] = f2b(wrow[rr] * v);
          }
        }
      }
    }
  }
}

// out[t] += y[t*2] + y[t*2+1]
__global__ __launch_bounds__(256)
void k_comb(float* __restrict__ out, const u16* __restrict__ y) {
  const int t = blockIdx.x;
  const int d = threadIdx.x * 8;
  const size_t b0 = (size_t)(t * 2) * DIMD + d;
  const size_t b1 = (size_t)(t * 2 + 1) * DIMD + d;
  ushort4 y0a = *(const ushort4*)&y[b0];
  ushort4 y0b = *(const ushort4*)&y[b0 + 4];
  ushort4 y1a = *(const ushort4*)&y[b1];
  ushort4 y1b = *(const ushort4*)&y[b1 + 4];
  float* op = out + (size_t)t * DIMD + d;
  float4 o0 = *(float4*)op;
  float4 o1 = *(float4*)(op + 4);
  o0.x += b2f(y0a.x) + b2f(y1a.x);
  o0.y += b2f(y0a.y) + b2f(y1a.y);
  o0.z += b2f(y0a.z) + b2f(y1a.z);
  o0.w += b2f(y0a.w) + b2f(y1a.w);
  o1.x += b2f(y0b.x) + b2f(y1b.x);
  o1.y += b2f(y0b.y) + b2f(y1b.y);
  o1.z += b2f(y0b.z) + b2f(y1b.z);
  o1.w += b2f(y0b.w) + b2f(y1b.w);
  *(float4*)op = o0;
  *(float4*)(op + 4) = o1;
}

// ---------------- launch ----------------

extern "C" void kernel_launch(void* const* d_in, const int* in_sizes, int n_in,
                              void* d_out, int out_size, void* d_ws, size_t ws_size,
                              hipStream_t stream) {
  const float* x   = (const float*)d_in[0];
  const float* gw  = (const float*)d_in[1];
  const float* sw1 = (const float*)d_in[2];
  const float* sw2 = (const float*)d_in[3];
  const float* w1  = (const float*)d_in[4];
  const float* w2  = (const float*)d_in[5];
  float* out = (float*)d_out;

  char* ws = (char*)d_ws;
  u16* xb    = (u16*)(ws);                         // 16 MB
  u16* hbS   = (u16*)(ws + (size_t)( 16 << 20));   // 16 MB [4096][2048]
  u16* hbR   = (u16*)(ws + (size_t)( 32 << 20));   // 20 MB [RMAX][1024]
  u16* y     = (u16*)(ws + (size_t)( 52 << 20));   // 32 MB [8192][2048]
  u16* sw1t  = (u16*)(ws + (size_t)( 84 << 20));   //  8 MB [2][1024][2048]
  u16* sw2ct = (u16*)(ws + (size_t)( 92 << 20));   //  8 MB [2048][2048]
  u16* w1t   = (u16*)(ws + (size_t)(100 << 20));   // 64 MB [16][1024][2048]
  u16* w2t   = (u16*)(ws + (size_t)(164 << 20));   // 64 MB [16][2048][1024]
  char* p = ws + (size_t)(228 << 20);
  int*   top2i   = (int*)p;    p += T_TOK * 2 * 4;
  float* top2w   = (float*)p;  p += T_TOK * 2 * 4;
  int*   perm    = (int*)p;    p += RMAX * 4;
  float* wrow    = (float*)p;  p += RMAX * 4;
  int*   slot    = (int*)p;    p += RMAX * 4;
  int*   cnt     = (int*)p;    p += 16 * 4;
  int*   fill    = (int*)p;    p += 16 * 4;
  int*   offs    = (int*)p;    p += 32 * 4;
  int*   tUe     = (int*)p;    p += MAXBLK * 4;
  int*   tUr     = (int*)p;    p += MAXBLK * 4;
  int*   tDe     = (int*)p;    p += MAXBLK * 4;
  int*   tDr     = (int*)p;    p += MAXBLK * 4;
  int*   nblk    = (int*)p;    p += 16 * 4;
  float* partial = (float*)p;  p += 256 * 16 * 4;

  k_init<<<(RMAX + 255) / 256, 256, 0, stream>>>(perm, cnt, fill);
  k_cvt<<<(T_TOK * DIMD / 4) / 256, 256, 0, stream>>>(x, xb);
  k_gate<<<T_TOK / 16, 256, 0, stream>>>(x, gw, top2i, top2w, cnt, partial);
  k_off<<<1, 64, 0, stream>>>(cnt, offs, tUe, tUr, tDe, tDr, nblk);
  k_fill<<<(T_TOK * 2 + 255) / 256, 256, 0, stream>>>(top2i, top2w, offs, fill, perm, wrow, slot);
  k_aux<<<1, 256, 0, stream>>>(partial, out + (size_t)T_TOK * DIMD);

  // weight transposes (fp32 [K][N] -> bf16 [n][k])
  k_tr<<<dim3(1024 / 64, 2048 / 64,  2), 256, 0, stream>>>(sw1, sw1t, 2048, 1024, 1024l * 2048, 2048);
  k_tr<<<dim3(2048 / 64, 1024 / 64,  2), 256, 0, stream>>>(sw2, sw2ct, 1024, 2048, 1024, 2048);
  k_tr<<<dim3(1024 / 64, 2048 / 64, 16), 256, 0, stream>>>(w1, w1t, 2048, 1024, 1024l * 2048, 2048);
  k_tr<<<dim3(2048 / 64, 1024 / 64, 16), 256, 0, stream>>>(w2, w2t, 1024, 2048, 2048l * 1024, 1024);

  // merged UP: routed (gather) + both shared experts
  k_gemm<0><<<dim3(144, 8), 256, 0, stream>>>(xb, xb, w1t, sw1t, hbR, hbS,
      perm, wrow, slot, tUe, tUr, nblk);
  // merged DOWN: shared (store out) + routed (weighted bf16 -> y)
  k_gemm<1><<<dim3(112, 16), 256, 0, stream>>>(hbR, hbS, w2t, sw2ct, y, out,
      perm, wrow, slot, tDe, tDr, nblk);
  // out += y(slot0) + y(slot1)
  k_comb<<<T_TOK, 256, 0, stream>>>(out, y);
}